// Round 7
// baseline (763.562 us; speedup 1.0000x reference)
//
#include <hip/hip_runtime.h>

#define DD 64
#define BKT_SHIFT 7                 // 128 nodes per bucket
#define BKT (1 << BKT_SHIFT)
#define TILE 4096                   // edges per partition block
#define MAXBK 1024                  // LDS arrays sized for NBK <= 1024
#define ROWF 68                     // padded LDS row stride (floats)

__device__ __forceinline__ float bflo(unsigned int u) {
    return __uint_as_float(u << 16);
}
__device__ __forceinline__ float bfhi(unsigned int u) {
    return __uint_as_float(u & 0xffff0000u);
}
__device__ __forceinline__ unsigned short f2bf(float f) {   // RNE
    unsigned int b = __float_as_uint(f);
    return (unsigned short)((b + 0x7fffu + ((b >> 16) & 1u)) >> 16);
}

// ---------------- bucket-count histogram (LDS-aggregated) ----------------
__global__ void zero_k(int* __restrict__ p, int n) {
    int i = blockIdx.x * blockDim.x + threadIdx.x;
    if (i < n) p[i] = 0;
}

__global__ void bhist_k(const int* __restrict__ dst, int* __restrict__ bcnt,
                        int E, int NBK) {
    __shared__ int h[MAXBK];
    int tid = threadIdx.x;
    for (int i = tid; i < NBK; i += 256) h[i] = 0;
    __syncthreads();
    for (int i = blockIdx.x * 256 + tid; i < E; i += gridDim.x * 256)
        atomicAdd(&h[dst[i] >> BKT_SHIFT], 1);
    __syncthreads();
    for (int i = tid; i < NBK; i += 256)
        if (h[i]) atomicAdd(&bcnt[i], h[i]);
}

// one-block exclusive scan of bucket counts -> bbase[0..NBK], copy to bcur
__global__ void bscan_k(const int* __restrict__ bcnt, int* __restrict__ bbase,
                        int* __restrict__ bcur, int NBK) {
    int lane = threadIdx.x;  // 64 threads
    int run = 0;
    for (int base = 0; base < NBK; base += 64) {
        int i = base + lane;
        int orig = (i < NBK) ? bcnt[i] : 0;
        int v = orig;
        #pragma unroll
        for (int off = 1; off < 64; off <<= 1) {
            int t = __shfl_up(v, off, 64);
            if (lane >= off) v += t;
        }
        if (i < NBK) {
            int ex = run + v - orig;
            bbase[i] = ex;
            bcur[i] = ex;
        }
        run += __shfl(v, 63, 64);
    }
    if (lane == 0) bbase[NBK] = run;   // == E
}

// ---------------- bucketed partition: packed edges grouped by dst bucket ----------------
// packed = (src << BKT_SHIFT) | (dst & (BKT-1));  requires N < 2^(31-BKT_SHIFT)
__global__ __launch_bounds__(256) void part_k(const int* __restrict__ src,
                                              const int* __restrict__ dst,
                                              int* __restrict__ bcur,
                                              int* __restrict__ bp,
                                              int E, int NBK) {
    __shared__ int hist[MAXBK];
    __shared__ int scanb[MAXBK];
    __shared__ int gbase[MAXBK];
    __shared__ int stage[TILE];             // 16 KB packed
    __shared__ unsigned short bstage[TILE]; // 8 KB bucket ids

    int tid = threadIdx.x;
    int tbase = blockIdx.x * TILE;
    int n = E - tbase;
    if (n > TILE) n = TILE;

    for (int i = tid; i < NBK; i += 256) hist[i] = 0;
    __syncthreads();

    int pv[TILE / 256];
    int pb[TILE / 256];
    #pragma unroll
    for (int e = 0; e < TILE / 256; ++e) {
        int i = tid + e * 256;
        pb[e] = -1;
        if (i < n) {
            int s = src[tbase + i];
            int d = dst[tbase + i];
            pv[e] = (s << BKT_SHIFT) | (d & (BKT - 1));
            pb[e] = d >> BKT_SHIFT;
            atomicAdd(&hist[pb[e]], 1);
        }
    }
    __syncthreads();

    // one-wave chunked exclusive scan of hist -> scanb
    if (tid < 64) {
        int run = 0;
        for (int base = 0; base < NBK; base += 64) {
            int i = base + tid;
            int orig = (i < NBK) ? hist[i] : 0;
            int v = orig;
            #pragma unroll
            for (int off = 1; off < 64; off <<= 1) {
                int t = __shfl_up(v, off, 64);
                if (tid >= off) v += t;
            }
            if (i < NBK) scanb[i] = run + v - orig;
            run += __shfl(v, 63, 64);
        }
    }
    __syncthreads();

    // reserve global ranges per bucket
    for (int i = tid; i < NBK; i += 256)
        if (hist[i]) gbase[i] = atomicAdd(&bcur[i], hist[i]);
    __syncthreads();
    for (int i = tid; i < NBK; i += 256) hist[i] = scanb[i];  // staging cursor
    __syncthreads();

    #pragma unroll
    for (int e = 0; e < TILE / 256; ++e) {
        if (pb[e] >= 0) {
            int r = atomicAdd(&hist[pb[e]], 1);
            stage[r] = pv[e];
            bstage[r] = (unsigned short)pb[e];
        }
    }
    __syncthreads();

    // contiguous runs per bucket
    for (int i = tid; i < n; i += 256) {
        int b = bstage[i];
        bp[gbase[b] + (i - scanb[b])] = stage[i];
    }
}

// ---------------- per-bucket node degrees -> dinv ----------------
__global__ void nodedeg_k(const int* __restrict__ bp, const int* __restrict__ bbase,
                          float* __restrict__ dinv, int N, int NBK) {
    __shared__ int cnt128[BKT];
    int k = blockIdx.x;
    int tid = threadIdx.x;
    int ebeg = bbase[k];
    int eend = bbase[k + 1];
    if (tid < BKT) cnt128[tid] = 0;
    __syncthreads();
    for (int i = ebeg + tid; i < eend; i += 256)
        atomicAdd(&cnt128[bp[i] & (BKT - 1)], 1);
    __syncthreads();
    if (tid < BKT) {
        int node = (k << BKT_SHIFT) + tid;
        if (node < N) dinv[node] = rsqrtf((float)(1 + cnt128[tid]));
    }
}

// ---------------- y = bf16( (z @ W^T) * dinv[n] ) ----------------
__global__ void gemm_k(const float* __restrict__ z, const float* __restrict__ W,
                       const float* __restrict__ dinv, ushort4* __restrict__ ybf,
                       int N) {
    __shared__ float Wt[64 * 68];
    __shared__ float zt[16 * 68];
    int tid = threadIdx.x;
    for (int i = tid; i < DD * DD; i += 256) {
        int d = i >> 6, k = i & 63;
        Wt[k * 68 + d] = W[i];
    }
    {
        int zr = blockIdx.x * 16 + (tid >> 4);
        float4 v = (zr < N) ? reinterpret_cast<const float4*>(z)[(size_t)zr * 16 + (tid & 15)]
                            : make_float4(0.f, 0.f, 0.f, 0.f);
        *reinterpret_cast<float4*>(&zt[(tid >> 4) * 68 + (tid & 15) * 4]) = v;
    }
    __syncthreads();
    int r = tid >> 4;
    int c = tid & 15;
    int row = blockIdx.x * 16 + r;
    float4 acc = make_float4(0.f, 0.f, 0.f, 0.f);
    #pragma unroll
    for (int k = 0; k < DD; ++k) {
        float zv = zt[r * 68 + k];
        float4 w = *reinterpret_cast<const float4*>(&Wt[k * 68 + c * 4]);
        acc.x = fmaf(zv, w.x, acc.x);
        acc.y = fmaf(zv, w.y, acc.y);
        acc.z = fmaf(zv, w.z, acc.z);
        acc.w = fmaf(zv, w.w, acc.w);
    }
    if (row < N) {
        float s = dinv[row];
        ushort4 o;
        o.x = f2bf(acc.x * s);
        o.y = f2bf(acc.y * s);
        o.z = f2bf(acc.z * s);
        o.w = f2bf(acc.w * s);
        ybf[(size_t)row * 16 + c] = o;   // cols 4c..4c+3
    }
}

// ---------------- bucket gather: LDS-accumulate unsorted bucket edges ----------------
// one block per bucket; acc[128][68] fp32 in LDS, seeded with self rows.
// A[n] = y[n] + sum_{s in N(n)} y[s];  out[n] = relu(A*dinv[n] + b)
__global__ __launch_bounds__(256) void bgather_k(const uint4* __restrict__ ybf,
                                                 const float* __restrict__ dinv,
                                                 const int* __restrict__ bp,
                                                 const int* __restrict__ bbase,
                                                 const float4* __restrict__ b4,
                                                 float4* __restrict__ out4, int N) {
    __shared__ float acc[BKT * ROWF];   // 34.8 KB
    int k = blockIdx.x;
    int tid = threadIdx.x;
    int ebeg = bbase[k];
    int eend = bbase[k + 1];
    int base = k << BKT_SHIFT;

    // seed with self row (zero for nodes >= N)
    for (int idx = tid; idx < BKT * 16; idx += 256) {   // 8 iters
        int nl = idx >> 4, c4 = idx & 15;
        int node = base + nl;
        float4 v = make_float4(0.f, 0.f, 0.f, 0.f);
        if (node < N) {
            ushort4 u = ((const ushort4*)ybf)[(size_t)node * 16 + c4];
            v.x = __uint_as_float((unsigned int)u.x << 16);
            v.y = __uint_as_float((unsigned int)u.y << 16);
            v.z = __uint_as_float((unsigned int)u.z << 16);
            v.w = __uint_as_float((unsigned int)u.w << 16);
        }
        *reinterpret_cast<float4*>(&acc[nl * ROWF + c4 * 4]) = v;
    }
    __syncthreads();

    // stream edges: 32 groups x 8 lanes; per edge one 128B row -> 8 LDS f32 atomics/lane
    int grp = tid >> 3;     // 0..31
    int c = tid & 7;        // col block (8 cols = one uint4)
    for (int i = ebeg + grp; i < eend; i += 32) {
        int v = bp[i];                       // uniform within 8-lane group
        int s = v >> BKT_SHIFT;
        float* dp = &acc[(v & (BKT - 1)) * ROWF + c * 8];
        uint4 r = ybf[(size_t)s * 8 + c];
        atomicAdd(dp + 0, bflo(r.x));
        atomicAdd(dp + 1, bfhi(r.x));
        atomicAdd(dp + 2, bflo(r.y));
        atomicAdd(dp + 3, bfhi(r.y));
        atomicAdd(dp + 4, bflo(r.z));
        atomicAdd(dp + 5, bfhi(r.z));
        atomicAdd(dp + 6, bflo(r.w));
        atomicAdd(dp + 7, bfhi(r.w));
    }
    __syncthreads();

    // epilogue: *dinv[dst] + bias, relu, coalesced store
    for (int idx = tid; idx < BKT * 16; idx += 256) {
        int nl = idx >> 4, c4 = idx & 15;
        int node = base + nl;
        if (node < N) {
            float4 a = *reinterpret_cast<const float4*>(&acc[nl * ROWF + c4 * 4]);
            float dn = dinv[node];
            float4 bb = b4[c4];
            float4 o;
            o.x = fmaxf(fmaf(a.x, dn, bb.x), 0.f);
            o.y = fmaxf(fmaf(a.y, dn, bb.y), 0.f);
            o.z = fmaxf(fmaf(a.z, dn, bb.z), 0.f);
            o.w = fmaxf(fmaf(a.w, dn, bb.w), 0.f);
            out4[(size_t)node * 16 + c4] = o;
        }
    }
}

// ---------------- launch ----------------

extern "C" void kernel_launch(void* const* d_in, const int* in_sizes, int n_in,
                              void* d_out, int out_size, void* d_ws, size_t ws_size,
                              hipStream_t stream) {
    const float* z = (const float*)d_in[0];
    const int* ei  = (const int*)d_in[1];
    const float* W = (const float*)d_in[2];
    const float* b = (const float*)d_in[3];
    float* out = (float*)d_out;

    const int N = in_sizes[0] / DD;
    const int E = in_sizes[1] / 2;
    const int* src = ei;
    const int* dst = ei + E;

    const int NBK = (N + BKT - 1) >> BKT_SHIFT;

    // workspace layout
    unsigned short* ybf = (unsigned short*)d_ws;      // 64N ushorts (bf16)
    float* dinv  = (float*)(ybf + (size_t)64 * N);    // N f
    int*   bcnt  = (int*)(dinv + N);                  // NBK
    int*   bbase = bcnt + NBK;                        // NBK+1
    int*   bcur  = bbase + NBK + 1;                   // NBK
    int*   bp    = bcur + NBK;                        // E

    zero_k<<<(NBK + 255) / 256, 256, 0, stream>>>(bcnt, NBK);
    bhist_k<<<256, 256, 0, stream>>>(dst, bcnt, E, NBK);
    bscan_k<<<1, 64, 0, stream>>>(bcnt, bbase, bcur, NBK);
    part_k<<<(E + TILE - 1) / TILE, 256, 0, stream>>>(src, dst, bcur, bp, E, NBK);
    nodedeg_k<<<NBK, 256, 0, stream>>>(bp, bbase, dinv, N, NBK);
    gemm_k<<<(N + 15) / 16, 256, 0, stream>>>(z, W, dinv, (ushort4*)ybf, N);
    bgather_k<<<NBK, 256, 0, stream>>>((const uint4*)ybf, dinv, bp, bbase,
                                       (const float4*)b, (float4*)out, N);
}

// Round 8
// 129.394 us; speedup vs baseline: 5.9011x; 5.9011x over previous
//
#include <hip/hip_runtime.h>

#define DD 64
#define BKT_SHIFT 8                 // 256 nodes per bucket
#define BKT (1 << BKT_SHIFT)
#define TILE 4096                   // edges per partition block
#define MAXBK 512                   // LDS arrays sized for NBK <= 512
#define PTHREADS 512                // part_k block size

__device__ __forceinline__ float bflo(unsigned int u) {
    return __uint_as_float(u << 16);
}
__device__ __forceinline__ float bfhi(unsigned int u) {
    return __uint_as_float(u & 0xffff0000u);
}
__device__ __forceinline__ unsigned short f2bf(float f) {   // RNE
    unsigned int b = __float_as_uint(f);
    return (unsigned short)((b + 0x7fffu + ((b >> 16) & 1u)) >> 16);
}

// ---------------- bucket-count histogram (LDS-aggregated) ----------------
__global__ void bhist_k(const int* __restrict__ dst, int* __restrict__ bcnt,
                        int E, int NBK) {
    __shared__ int h[MAXBK];
    int tid = threadIdx.x;
    for (int i = tid; i < NBK; i += 256) h[i] = 0;
    __syncthreads();
    for (int i = blockIdx.x * 256 + tid; i < E; i += gridDim.x * 256)
        atomicAdd(&h[dst[i] >> BKT_SHIFT], 1);
    __syncthreads();
    for (int i = tid; i < NBK; i += 256)
        if (h[i]) atomicAdd(&bcnt[i], h[i]);
}

// one-block exclusive scan of bucket counts -> bbase[0..NBK], copy to bcur
__global__ void bscan_k(const int* __restrict__ bcnt, int* __restrict__ bbase,
                        int* __restrict__ bcur, int NBK) {
    int lane = threadIdx.x;  // 64 threads
    int run = 0;
    for (int base = 0; base < NBK; base += 64) {
        int i = base + lane;
        int orig = (i < NBK) ? bcnt[i] : 0;
        int v = orig;
        #pragma unroll
        for (int off = 1; off < 64; off <<= 1) {
            int t = __shfl_up(v, off, 64);
            if (lane >= off) v += t;
        }
        if (i < NBK) {
            int ex = run + v - orig;
            bbase[i] = ex;
            bcur[i] = ex;
        }
        run += __shfl(v, 63, 64);
    }
    if (lane == 0) bbase[NBK] = run;   // == E
}

// ---------------- bucketed partition: packed edges grouped by dst bucket ----------------
// packed = (src << BKT_SHIFT) | (dst & (BKT-1));  requires N < 2^(31-BKT_SHIFT)
__global__ __launch_bounds__(PTHREADS) void part_k(const int* __restrict__ src,
                                                   const int* __restrict__ dst,
                                                   int* __restrict__ bcur,
                                                   int* __restrict__ bp,
                                                   int E, int NBK) {
    __shared__ int hist[MAXBK];
    __shared__ int scanb[MAXBK];
    __shared__ int gbase[MAXBK];
    __shared__ int stage[TILE];             // 16 KB packed
    __shared__ unsigned short bstage[TILE]; // 8 KB bucket ids

    int tid = threadIdx.x;
    int tbase = blockIdx.x * TILE;
    int n = E - tbase;
    if (n > TILE) n = TILE;

    for (int i = tid; i < NBK; i += PTHREADS) hist[i] = 0;
    __syncthreads();

    int pv[TILE / PTHREADS];
    int pb[TILE / PTHREADS];
    #pragma unroll
    for (int e = 0; e < TILE / PTHREADS; ++e) {
        int i = tid + e * PTHREADS;
        pb[e] = -1;
        if (i < n) {
            int s = src[tbase + i];
            int d = dst[tbase + i];
            pv[e] = (s << BKT_SHIFT) | (d & (BKT - 1));
            pb[e] = d >> BKT_SHIFT;
            atomicAdd(&hist[pb[e]], 1);
        }
    }
    __syncthreads();

    // one-wave chunked exclusive scan of hist -> scanb
    if (tid < 64) {
        int run = 0;
        for (int base = 0; base < NBK; base += 64) {
            int i = base + tid;
            int orig = (i < NBK) ? hist[i] : 0;
            int v = orig;
            #pragma unroll
            for (int off = 1; off < 64; off <<= 1) {
                int t = __shfl_up(v, off, 64);
                if (tid >= off) v += t;
            }
            if (i < NBK) scanb[i] = run + v - orig;
            run += __shfl(v, 63, 64);
        }
    }
    __syncthreads();

    // reserve global ranges per bucket
    for (int i = tid; i < NBK; i += PTHREADS)
        if (hist[i]) gbase[i] = atomicAdd(&bcur[i], hist[i]);
    __syncthreads();
    for (int i = tid; i < NBK; i += PTHREADS) hist[i] = scanb[i];  // staging cursor
    __syncthreads();

    #pragma unroll
    for (int e = 0; e < TILE / PTHREADS; ++e) {
        if (pb[e] >= 0) {
            int r = atomicAdd(&hist[pb[e]], 1);
            stage[r] = pv[e];
            bstage[r] = (unsigned short)pb[e];
        }
    }
    __syncthreads();

    // contiguous runs per bucket (avg run ~10 edges -> coalesced-ish)
    for (int i = tid; i < n; i += PTHREADS) {
        int b = bstage[i];
        bp[gbase[b] + (i - scanb[b])] = stage[i];
    }
}

// ---------------- per-bucket: node hist + scan + dinv + rs + counting-sort fill ----------------
__global__ void bucket_k(const int* __restrict__ bp, const int* __restrict__ bbase,
                         int* __restrict__ rs, float* __restrict__ dinv,
                         int* __restrict__ ss, int N, int E, int NBK) {
    __shared__ int cnt[BKT];    // 256
    __shared__ int excl[BKT];
    __shared__ int cur[BKT];
    int k = blockIdx.x;
    int ebeg = bbase[k];
    int eend = bbase[k + 1];
    int tid = threadIdx.x;      // 256 threads == BKT

    cnt[tid] = 0;
    __syncthreads();
    for (int i = ebeg + tid; i < eend; i += 256)
        atomicAdd(&cnt[bp[i] & (BKT - 1)], 1);
    __syncthreads();

    excl[tid] = cnt[tid];
    __syncthreads();
    #pragma unroll
    for (int off = 1; off < BKT; off <<= 1) {
        int t = (tid >= off) ? excl[tid - off] : 0;
        __syncthreads();
        excl[tid] += t;
        __syncthreads();
    }
    {
        int c = cnt[tid];
        int ex = excl[tid] - c;     // exclusive
        cur[tid] = ex;
        int node = (k << BKT_SHIFT) + tid;
        if (node < N) {
            rs[node] = ebeg + ex;
            dinv[node] = rsqrtf((float)(1 + c));
        }
    }
    if (k == NBK - 1 && tid == 0) rs[N] = E;
    __syncthreads();

    for (int i = ebeg + tid; i < eend; i += 256) {
        int v = bp[i];
        int l = v & (BKT - 1);
        int pos = atomicAdd(&cur[l], 1);
        ss[ebeg + pos] = v >> BKT_SHIFT;   // src index
    }
}

// ---------------- y = bf16( (z @ W^T) * dinv[n] ) ----------------
__global__ void gemm_k(const float* __restrict__ z, const float* __restrict__ W,
                       const float* __restrict__ dinv, ushort4* __restrict__ ybf,
                       int N) {
    __shared__ float Wt[64 * 68];
    __shared__ float zt[16 * 68];
    int tid = threadIdx.x;
    for (int i = tid; i < DD * DD; i += 256) {
        int d = i >> 6, k = i & 63;
        Wt[k * 68 + d] = W[i];
    }
    {
        int zr = blockIdx.x * 16 + (tid >> 4);
        float4 v = (zr < N) ? reinterpret_cast<const float4*>(z)[(size_t)zr * 16 + (tid & 15)]
                            : make_float4(0.f, 0.f, 0.f, 0.f);
        *reinterpret_cast<float4*>(&zt[(tid >> 4) * 68 + (tid & 15) * 4]) = v;
    }
    __syncthreads();
    int r = tid >> 4;
    int c = tid & 15;
    int row = blockIdx.x * 16 + r;
    float4 acc = make_float4(0.f, 0.f, 0.f, 0.f);
    #pragma unroll
    for (int k = 0; k < DD; ++k) {
        float zv = zt[r * 68 + k];
        float4 w = *reinterpret_cast<const float4*>(&Wt[k * 68 + c * 4]);
        acc.x = fmaf(zv, w.x, acc.x);
        acc.y = fmaf(zv, w.y, acc.y);
        acc.z = fmaf(zv, w.z, acc.z);
        acc.w = fmaf(zv, w.w, acc.w);
    }
    if (row < N) {
        float s = dinv[row];
        ushort4 o;
        o.x = f2bf(acc.x * s);
        o.y = f2bf(acc.y * s);
        o.z = f2bf(acc.z * s);
        o.w = f2bf(acc.w * s);
        ybf[(size_t)row * 16 + c] = o;   // cols 4c..4c+3
    }
}

// ---------------- fused pull-gather: 8-lane group per node, no shuffles ----------------
// group walks its node's contiguous sorted edge run; lane owns 8 cols (one uint4).
// out[n] = relu( dinv[n] * ( y[n] + sum_s y[s] ) + b )
__global__ void gather_k(const uint4* __restrict__ ybf, const float* __restrict__ dinv,
                         const int* __restrict__ rs, const int* __restrict__ ss,
                         const float4* __restrict__ b4, float4* __restrict__ out4, int N) {
    int tid = threadIdx.x;
    int g = tid >> 3;           // 0..31: node slot in block
    int c = tid & 7;            // col block (8 bf16 cols = 16B)
    int n = blockIdx.x * 32 + g;
    if (n >= N) return;
    int beg = rs[n];
    int end = rs[n + 1];
    // self-loop message seeds the accumulator
    uint4 v = ybf[(size_t)n * 8 + c];
    float4 a0 = make_float4(bflo(v.x), bfhi(v.x), bflo(v.y), bfhi(v.y));
    float4 a1 = make_float4(bflo(v.z), bfhi(v.z), bflo(v.w), bfhi(v.w));
    for (int j = beg; j < end; ++j) {
        int s = ss[j];                       // uniform within group -> broadcast
        uint4 r = ybf[(size_t)s * 8 + c];    // 128B row per edge across group
        a0.x += bflo(r.x); a0.y += bfhi(r.x);
        a0.z += bflo(r.y); a0.w += bfhi(r.y);
        a1.x += bflo(r.z); a1.y += bfhi(r.z);
        a1.z += bflo(r.w); a1.w += bfhi(r.w);
    }
    float dn = dinv[n];
    float4 bb0 = b4[2 * c];
    float4 bb1 = b4[2 * c + 1];
    float4 o0, o1;
    o0.x = fmaxf(fmaf(a0.x, dn, bb0.x), 0.f);
    o0.y = fmaxf(fmaf(a0.y, dn, bb0.y), 0.f);
    o0.z = fmaxf(fmaf(a0.z, dn, bb0.z), 0.f);
    o0.w = fmaxf(fmaf(a0.w, dn, bb0.w), 0.f);
    o1.x = fmaxf(fmaf(a1.x, dn, bb1.x), 0.f);
    o1.y = fmaxf(fmaf(a1.y, dn, bb1.y), 0.f);
    o1.z = fmaxf(fmaf(a1.z, dn, bb1.z), 0.f);
    o1.w = fmaxf(fmaf(a1.w, dn, bb1.w), 0.f);
    out4[(size_t)n * 16 + 2 * c] = o0;
    out4[(size_t)n * 16 + 2 * c + 1] = o1;
}

// ---------------- launch ----------------

extern "C" void kernel_launch(void* const* d_in, const int* in_sizes, int n_in,
                              void* d_out, int out_size, void* d_ws, size_t ws_size,
                              hipStream_t stream) {
    const float* z = (const float*)d_in[0];
    const int* ei  = (const int*)d_in[1];
    const float* W = (const float*)d_in[2];
    const float* b = (const float*)d_in[3];
    float* out = (float*)d_out;

    const int N = in_sizes[0] / DD;
    const int E = in_sizes[1] / 2;
    const int* src = ei;
    const int* dst = ei + E;

    const int NBK = (N + BKT - 1) >> BKT_SHIFT;

    // workspace layout
    unsigned short* ybf = (unsigned short*)d_ws;      // 64N ushorts (bf16)
    float* dinv  = (float*)(ybf + (size_t)64 * N);    // N f
    int*   rs    = (int*)(dinv + N);                  // N+1
    int*   bcnt  = rs + N + 1;                        // NBK
    int*   bbase = bcnt + NBK;                        // NBK+1
    int*   bcur  = bbase + NBK + 1;                   // NBK
    int*   ss    = bcur + NBK;                        // E
    int*   bp    = ss + E;                            // E

    hipMemsetAsync(bcnt, 0, sizeof(int) * NBK, stream);
    bhist_k<<<256, 256, 0, stream>>>(dst, bcnt, E, NBK);
    bscan_k<<<1, 64, 0, stream>>>(bcnt, bbase, bcur, NBK);
    part_k<<<(E + TILE - 1) / TILE, PTHREADS, 0, stream>>>(src, dst, bcur, bp, E, NBK);
    bucket_k<<<NBK, BKT, 0, stream>>>(bp, bbase, rs, dinv, ss, N, E, NBK);
    gemm_k<<<(N + 15) / 16, 256, 0, stream>>>(z, W, dinv, (ushort4*)ybf, N);
    gather_k<<<(N + 31) / 32, 256, 0, stream>>>((const uint4*)ybf, dinv, rs, ss,
                                                (const float4*)b, (float4*)out, N);
}

// Round 9
// 96.085 us; speedup vs baseline: 7.9467x; 1.3467x over previous
//
#include <hip/hip_runtime.h>

#define DD 64
#define BKT_SHIFT 8                 // 256 nodes per bucket
#define BKT (1 << BKT_SHIFT)
#define CAP 5120                    // edge capacity per bucket region (mean 4092, +16 sigma)
#define TILE 4096                   // edges per partition block
#define MAXBK 512                   // LDS arrays sized for NBK <= 512
#define PTHREADS 512                // part_k block size

__device__ __forceinline__ float bflo(unsigned int u) {
    return __uint_as_float(u << 16);
}
__device__ __forceinline__ float bfhi(unsigned int u) {
    return __uint_as_float(u & 0xffff0000u);
}
__device__ __forceinline__ unsigned short f2bf(float f) {   // RNE
    unsigned int b = __float_as_uint(f);
    return (unsigned short)((b + 0x7fffu + ((b >> 16) & 1u)) >> 16);
}
__device__ __forceinline__ void acc_row(uint4 r, float4& lo, float4& hi) {
    lo.x += bflo(r.x); lo.y += bfhi(r.x);
    lo.z += bflo(r.y); lo.w += bfhi(r.y);
    hi.x += bflo(r.z); hi.y += bfhi(r.z);
    hi.z += bflo(r.w); hi.w += bfhi(r.w);
}

// ---------------- init per-bucket cursors to region bases ----------------
__global__ void init_k(int* __restrict__ bcur, int NBK) {
    int i = blockIdx.x * blockDim.x + threadIdx.x;
    if (i < NBK) bcur[i] = i * CAP;
}

// ---------------- bucketed partition into capacity-slotted regions ----------------
// packed = (src << BKT_SHIFT) | (dst & (BKT-1))
__global__ __launch_bounds__(PTHREADS) void part_k(const int* __restrict__ src,
                                                   const int* __restrict__ dst,
                                                   int* __restrict__ bcur,
                                                   int* __restrict__ bp,
                                                   int E, int NBK) {
    __shared__ int hist[MAXBK];
    __shared__ int scanb[MAXBK];
    __shared__ int gbase[MAXBK];
    __shared__ int stage[TILE];             // 16 KB packed
    __shared__ unsigned short bstage[TILE]; // 8 KB bucket ids

    int tid = threadIdx.x;
    int tbase = blockIdx.x * TILE;
    int n = E - tbase;
    if (n > TILE) n = TILE;

    for (int i = tid; i < NBK; i += PTHREADS) hist[i] = 0;
    __syncthreads();

    int pv[TILE / PTHREADS];
    int pb[TILE / PTHREADS];
    #pragma unroll
    for (int e = 0; e < TILE / PTHREADS; ++e) {
        int i = tid + e * PTHREADS;
        pb[e] = -1;
        if (i < n) {
            int s = src[tbase + i];
            int d = dst[tbase + i];
            pv[e] = (s << BKT_SHIFT) | (d & (BKT - 1));
            pb[e] = d >> BKT_SHIFT;
            atomicAdd(&hist[pb[e]], 1);
        }
    }
    __syncthreads();

    // one-wave chunked exclusive scan of hist -> scanb
    if (tid < 64) {
        int run = 0;
        for (int base = 0; base < NBK; base += 64) {
            int i = base + tid;
            int orig = (i < NBK) ? hist[i] : 0;
            int v = orig;
            #pragma unroll
            for (int off = 1; off < 64; off <<= 1) {
                int t = __shfl_up(v, off, 64);
                if (tid >= off) v += t;
            }
            if (i < NBK) scanb[i] = run + v - orig;
            run += __shfl(v, 63, 64);
        }
    }
    __syncthreads();

    // reserve ranges in each bucket's region
    for (int i = tid; i < NBK; i += PTHREADS)
        if (hist[i]) gbase[i] = atomicAdd(&bcur[i], hist[i]);
    __syncthreads();
    for (int i = tid; i < NBK; i += PTHREADS) hist[i] = scanb[i];  // staging cursor
    __syncthreads();

    #pragma unroll
    for (int e = 0; e < TILE / PTHREADS; ++e) {
        if (pb[e] >= 0) {
            int r = atomicAdd(&hist[pb[e]], 1);
            stage[r] = pv[e];
            bstage[r] = (unsigned short)pb[e];
        }
    }
    __syncthreads();

    // contiguous runs per bucket
    for (int i = tid; i < n; i += PTHREADS) {
        int b = bstage[i];
        bp[gbase[b] + (i - scanb[b])] = stage[i];
    }
}

// ---------------- per-bucket: node hist + wave scan + dinv + rs/re + fill ----------------
__global__ __launch_bounds__(BKT) void bucket_k(const int* __restrict__ bp,
                                                const int* __restrict__ bcur,
                                                int* __restrict__ rs, int* __restrict__ re,
                                                float* __restrict__ dinv,
                                                int* __restrict__ ss, int N) {
    __shared__ int cnt[BKT];
    __shared__ int cur[BKT];
    __shared__ int wsum[4];
    int k = blockIdx.x;
    int ebeg = k * CAP;
    int eend = bcur[k];
    int tid = threadIdx.x;      // 256 threads == BKT
    int lane = tid & 63;
    int wid = tid >> 6;

    cnt[tid] = 0;
    __syncthreads();
    for (int i = ebeg + tid; i < eend; i += BKT)
        atomicAdd(&cnt[bp[i] & (BKT - 1)], 1);
    __syncthreads();

    // 4-wave scan: shfl within wave, combine via wsum
    int c = cnt[tid];
    int v = c;
    #pragma unroll
    for (int off = 1; off < 64; off <<= 1) {
        int t = __shfl_up(v, off, 64);
        if (lane >= off) v += t;
    }
    if (lane == 63) wsum[wid] = v;
    __syncthreads();
    int woff = 0;
    #pragma unroll
    for (int w = 0; w < 3; ++w)
        if (w < wid) woff += wsum[w];
    int ex = woff + v - c;   // exclusive prefix

    cur[tid] = ex;
    int node = (k << BKT_SHIFT) + tid;
    if (node < N) {
        rs[node] = ebeg + ex;
        re[node] = ebeg + ex + c;
        dinv[node] = rsqrtf((float)(1 + c));
    }
    __syncthreads();

    for (int i = ebeg + tid; i < eend; i += BKT) {
        int pvv = bp[i];
        int l = pvv & (BKT - 1);
        int pos = atomicAdd(&cur[l], 1);
        ss[ebeg + pos] = pvv >> BKT_SHIFT;   // src index
    }
}

// ---------------- y = bf16( (z @ W^T) * dinv[n] ), 32 rows/block ----------------
__global__ __launch_bounds__(512) void gemm_k(const float* __restrict__ z,
                                              const float* __restrict__ W,
                                              const float* __restrict__ dinv,
                                              ushort4* __restrict__ ybf, int N) {
    __shared__ float Wt[64 * 68];
    __shared__ float zt[32 * 68];
    int tid = threadIdx.x;
    for (int i = tid; i < DD * DD; i += 512) {
        int d = i >> 6, k = i & 63;
        Wt[k * 68 + d] = W[i];
    }
    {
        int zr = blockIdx.x * 32 + (tid >> 4);
        float4 v = (zr < N) ? reinterpret_cast<const float4*>(z)[(size_t)zr * 16 + (tid & 15)]
                            : make_float4(0.f, 0.f, 0.f, 0.f);
        *reinterpret_cast<float4*>(&zt[(tid >> 4) * 68 + (tid & 15) * 4]) = v;
    }
    __syncthreads();
    int r = tid >> 4;
    int c = tid & 15;
    int row = blockIdx.x * 32 + r;
    float4 acc = make_float4(0.f, 0.f, 0.f, 0.f);
    #pragma unroll
    for (int k = 0; k < DD; ++k) {
        float zv = zt[r * 68 + k];
        float4 w = *reinterpret_cast<const float4*>(&Wt[k * 68 + c * 4]);
        acc.x = fmaf(zv, w.x, acc.x);
        acc.y = fmaf(zv, w.y, acc.y);
        acc.z = fmaf(zv, w.z, acc.z);
        acc.w = fmaf(zv, w.w, acc.w);
    }
    if (row < N) {
        float s = dinv[row];
        ushort4 o;
        o.x = f2bf(acc.x * s);
        o.y = f2bf(acc.y * s);
        o.z = f2bf(acc.z * s);
        o.w = f2bf(acc.w * s);
        ybf[(size_t)row * 16 + c] = o;
    }
}

// ---------------- fused pull-gather: 8-lane group per node, 4-deep pipeline ----------------
__global__ void gather_k(const uint4* __restrict__ ybf, const float* __restrict__ dinv,
                         const int* __restrict__ rs, const int* __restrict__ re,
                         const int* __restrict__ ss, const float4* __restrict__ b4,
                         float4* __restrict__ out4, int N) {
    int tid = threadIdx.x;
    int g = tid >> 3;           // 0..31: node slot in block
    int c = tid & 7;            // col block (8 bf16 cols = 16B)
    int n = blockIdx.x * 32 + g;
    if (n >= N) return;
    int beg = rs[n];
    int end = re[n];
    // self-loop message seeds accumulator set A
    uint4 v = ybf[(size_t)n * 8 + c];
    float4 a0 = make_float4(bflo(v.x), bfhi(v.x), bflo(v.y), bfhi(v.y));
    float4 a1 = make_float4(bflo(v.z), bfhi(v.z), bflo(v.w), bfhi(v.w));
    float4 e0 = make_float4(0.f, 0.f, 0.f, 0.f);
    float4 e1 = e0;
    int j = beg;
    for (; j + 3 < end; j += 4) {
        int s0 = ss[j], s1 = ss[j + 1], s2 = ss[j + 2], s3 = ss[j + 3];
        uint4 r0 = ybf[(size_t)s0 * 8 + c];
        uint4 r1 = ybf[(size_t)s1 * 8 + c];
        uint4 r2 = ybf[(size_t)s2 * 8 + c];
        uint4 r3 = ybf[(size_t)s3 * 8 + c];
        acc_row(r0, a0, a1);
        acc_row(r1, e0, e1);
        acc_row(r2, a0, a1);
        acc_row(r3, e0, e1);
    }
    for (; j < end; ++j) {
        int s = ss[j];
        uint4 r = ybf[(size_t)s * 8 + c];
        acc_row(r, a0, a1);
    }
    a0.x += e0.x; a0.y += e0.y; a0.z += e0.z; a0.w += e0.w;
    a1.x += e1.x; a1.y += e1.y; a1.z += e1.z; a1.w += e1.w;

    float dn = dinv[n];
    float4 bb0 = b4[2 * c];
    float4 bb1 = b4[2 * c + 1];
    float4 o0, o1;
    o0.x = fmaxf(fmaf(a0.x, dn, bb0.x), 0.f);
    o0.y = fmaxf(fmaf(a0.y, dn, bb0.y), 0.f);
    o0.z = fmaxf(fmaf(a0.z, dn, bb0.z), 0.f);
    o0.w = fmaxf(fmaf(a0.w, dn, bb0.w), 0.f);
    o1.x = fmaxf(fmaf(a1.x, dn, bb1.x), 0.f);
    o1.y = fmaxf(fmaf(a1.y, dn, bb1.y), 0.f);
    o1.z = fmaxf(fmaf(a1.z, dn, bb1.z), 0.f);
    o1.w = fmaxf(fmaf(a1.w, dn, bb1.w), 0.f);
    out4[(size_t)n * 16 + 2 * c] = o0;
    out4[(size_t)n * 16 + 2 * c + 1] = o1;
}

// ---------------- launch ----------------

extern "C" void kernel_launch(void* const* d_in, const int* in_sizes, int n_in,
                              void* d_out, int out_size, void* d_ws, size_t ws_size,
                              hipStream_t stream) {
    const float* z = (const float*)d_in[0];
    const int* ei  = (const int*)d_in[1];
    const float* W = (const float*)d_in[2];
    const float* b = (const float*)d_in[3];
    float* out = (float*)d_out;

    const int N = in_sizes[0] / DD;
    const int E = in_sizes[1] / 2;
    const int* src = ei;
    const int* dst = ei + E;

    const int NBK = (N + BKT - 1) >> BKT_SHIFT;

    // workspace layout
    unsigned short* ybf = (unsigned short*)d_ws;      // 64N ushorts (bf16)
    float* dinv  = (float*)(ybf + (size_t)64 * N);    // N f
    int*   rs    = (int*)(dinv + N);                  // N
    int*   re    = rs + N;                            // N
    int*   bcur  = re + N;                            // NBK
    int*   ss    = bcur + NBK;                        // NBK*CAP
    int*   bp    = ss + (size_t)NBK * CAP;            // NBK*CAP

    init_k<<<(NBK + 255) / 256, 256, 0, stream>>>(bcur, NBK);
    part_k<<<(E + TILE - 1) / TILE, PTHREADS, 0, stream>>>(src, dst, bcur, bp, E, NBK);
    bucket_k<<<NBK, BKT, 0, stream>>>(bp, bcur, rs, re, dinv, ss, N);
    gemm_k<<<(N + 31) / 32, 512, 0, stream>>>(z, W, dinv, (ushort4*)ybf, N);
    gather_k<<<(N + 31) / 32, 256, 0, stream>>>((const uint4*)ybf, dinv, rs, re, ss,
                                                (const float4*)b, (float4*)out, N);
}

// Round 10
// 93.549 us; speedup vs baseline: 8.1622x; 1.0271x over previous
//
#include <hip/hip_runtime.h>

#define DD 64
#define BSH 7                   // 128 nodes per bucket
#define GBKT 128                // nodes per bucket
#define CAP 2560                // edge capacity per bucket region (mean 2048, +11 sigma)
#define TILE 4096               // edges per partition block
#define PTHREADS 512            // part_k block size
#define MAXBK 1024              // part_k LDS arrays sized for NBK <= 1024

__device__ __forceinline__ float bflo(unsigned int u) {
    return __uint_as_float(u << 16);
}
__device__ __forceinline__ float bfhi(unsigned int u) {
    return __uint_as_float(u & 0xffff0000u);
}
__device__ __forceinline__ unsigned short f2bf(float f) {   // RNE
    unsigned int b = __float_as_uint(f);
    return (unsigned short)((b + 0x7fffu + ((b >> 16) & 1u)) >> 16);
}
__device__ __forceinline__ void acc_row(uint4 r, float4& lo, float4& hi) {
    lo.x += bflo(r.x); lo.y += bfhi(r.x);
    lo.z += bflo(r.y); lo.w += bfhi(r.y);
    hi.x += bflo(r.z); hi.y += bfhi(r.z);
    hi.z += bflo(r.w); hi.w += bfhi(r.w);
}

// ---------------- init per-bucket cursors to region bases ----------------
__global__ void init_k(int* __restrict__ bcur, int NBK) {
    int i = blockIdx.x * blockDim.x + threadIdx.x;
    if (i < NBK) bcur[i] = i * CAP;
}

// ---------------- bucketed partition into capacity-slotted regions ----------------
// packed = (src << BSH) | (dst & (GBKT-1))
__global__ __launch_bounds__(PTHREADS) void part_k(const int* __restrict__ src,
                                                   const int* __restrict__ dst,
                                                   int* __restrict__ bcur,
                                                   int* __restrict__ bp,
                                                   int E, int NBK) {
    __shared__ int hist[MAXBK];
    __shared__ int scanb[MAXBK];
    __shared__ int gbase[MAXBK];
    __shared__ int stage[TILE];             // 16 KB packed
    __shared__ unsigned short bstage[TILE]; // 8 KB bucket ids

    int tid = threadIdx.x;
    int tbase = blockIdx.x * TILE;
    int n = E - tbase;
    if (n > TILE) n = TILE;

    for (int i = tid; i < NBK; i += PTHREADS) hist[i] = 0;
    __syncthreads();

    int pv[TILE / PTHREADS];
    int pb[TILE / PTHREADS];
    #pragma unroll
    for (int e = 0; e < TILE / PTHREADS; ++e) {
        int i = tid + e * PTHREADS;
        pb[e] = -1;
        if (i < n) {
            int s = src[tbase + i];
            int d = dst[tbase + i];
            pv[e] = (s << BSH) | (d & (GBKT - 1));
            pb[e] = d >> BSH;
            atomicAdd(&hist[pb[e]], 1);
        }
    }
    __syncthreads();

    // one-wave chunked exclusive scan of hist -> scanb
    if (tid < 64) {
        int run = 0;
        for (int base = 0; base < NBK; base += 64) {
            int i = base + tid;
            int orig = (i < NBK) ? hist[i] : 0;
            int v = orig;
            #pragma unroll
            for (int off = 1; off < 64; off <<= 1) {
                int t = __shfl_up(v, off, 64);
                if (tid >= off) v += t;
            }
            if (i < NBK) scanb[i] = run + v - orig;
            run += __shfl(v, 63, 64);
        }
    }
    __syncthreads();

    // reserve ranges in each bucket's region
    for (int i = tid; i < NBK; i += PTHREADS)
        if (hist[i]) gbase[i] = atomicAdd(&bcur[i], hist[i]);
    __syncthreads();
    for (int i = tid; i < NBK; i += PTHREADS) hist[i] = scanb[i];  // staging cursor
    __syncthreads();

    #pragma unroll
    for (int e = 0; e < TILE / PTHREADS; ++e) {
        if (pb[e] >= 0) {
            int r = atomicAdd(&hist[pb[e]], 1);
            stage[r] = pv[e];
            bstage[r] = (unsigned short)pb[e];
        }
    }
    __syncthreads();

    // contiguous runs per bucket
    for (int i = tid; i < n; i += PTHREADS) {
        int b = bstage[i];
        bp[gbase[b] + (i - scanb[b])] = stage[i];
    }
}

// ---------------- per-bucket node degrees -> dinv (needed by gemm prescale) ----------------
__global__ void nodedeg_k(const int* __restrict__ bp, const int* __restrict__ bcur,
                          float* __restrict__ dinv, int N) {
    __shared__ int cnt[GBKT];
    int k = blockIdx.x;
    int tid = threadIdx.x;
    int ebeg = k * CAP;
    int eend = bcur[k];
    if (tid < GBKT) cnt[tid] = 0;
    __syncthreads();
    for (int i = ebeg + tid; i < eend; i += 256)
        atomicAdd(&cnt[bp[i] & (GBKT - 1)], 1);
    __syncthreads();
    if (tid < GBKT) {
        int node = (k << BSH) + tid;
        if (node < N) dinv[node] = rsqrtf((float)(1 + cnt[tid]));
    }
}

// ---------------- y = bf16( (z @ W^T) * dinv[n] ), 32 rows/block ----------------
__global__ __launch_bounds__(512) void gemm_k(const float* __restrict__ z,
                                              const float* __restrict__ W,
                                              const float* __restrict__ dinv,
                                              ushort4* __restrict__ ybf, int N) {
    __shared__ float Wt[64 * 68];
    __shared__ float zt[32 * 68];
    int tid = threadIdx.x;
    for (int i = tid; i < DD * DD; i += 512) {
        int d = i >> 6, k = i & 63;
        Wt[k * 68 + d] = W[i];
    }
    {
        int zr = blockIdx.x * 32 + (tid >> 4);
        float4 v = (zr < N) ? reinterpret_cast<const float4*>(z)[(size_t)zr * 16 + (tid & 15)]
                            : make_float4(0.f, 0.f, 0.f, 0.f);
        *reinterpret_cast<float4*>(&zt[(tid >> 4) * 68 + (tid & 15) * 4]) = v;
    }
    __syncthreads();
    int r = tid >> 4;
    int c = tid & 15;
    int row = blockIdx.x * 32 + r;
    float4 acc = make_float4(0.f, 0.f, 0.f, 0.f);
    #pragma unroll
    for (int k = 0; k < DD; ++k) {
        float zv = zt[r * 68 + k];
        float4 w = *reinterpret_cast<const float4*>(&Wt[k * 68 + c * 4]);
        acc.x = fmaf(zv, w.x, acc.x);
        acc.y = fmaf(zv, w.y, acc.y);
        acc.z = fmaf(zv, w.z, acc.z);
        acc.w = fmaf(zv, w.w, acc.w);
    }
    if (row < N) {
        float s = dinv[row];
        ushort4 o;
        o.x = f2bf(acc.x * s);
        o.y = f2bf(acc.y * s);
        o.z = f2bf(acc.z * s);
        o.w = f2bf(acc.w * s);
        ybf[(size_t)row * 16 + c] = o;
    }
}

// ---------------- fused per-bucket sort (LDS) + gather + epilogue ----------------
// one block per 128-node bucket; sorted edge list lives in LDS only.
__global__ __launch_bounds__(256) void bg_k(const uint4* __restrict__ ybf,
                                            const int* __restrict__ bp,
                                            const int* __restrict__ bcur,
                                            const float4* __restrict__ b4,
                                            float4* __restrict__ out4, int N) {
    __shared__ int cnt[GBKT];
    __shared__ int excl[GBKT];
    __shared__ int cur[GBKT];
    __shared__ int sorted[CAP];   // 10 KB: src ids sorted by local dst
    __shared__ int nextn;
    int k = blockIdx.x;
    int tid = threadIdx.x;
    int ebeg = k * CAP;
    int eend = bcur[k];
    int base = k << BSH;

    if (tid < GBKT) cnt[tid] = 0;
    if (tid == 0) nextn = 0;
    __syncthreads();
    for (int i = ebeg + tid; i < eend; i += 256)
        atomicAdd(&cnt[bp[i] & (GBKT - 1)], 1);
    __syncthreads();

    // 128-wide ladder scan (inclusive) then to exclusive
    if (tid < GBKT) excl[tid] = cnt[tid];
    __syncthreads();
    #pragma unroll
    for (int off = 1; off < GBKT; off <<= 1) {
        int t = (tid < GBKT && tid >= off) ? excl[tid - off] : 0;
        __syncthreads();
        if (tid < GBKT) excl[tid] += t;
        __syncthreads();
    }
    if (tid < GBKT) {
        excl[tid] -= cnt[tid];
        cur[tid] = excl[tid];
    }
    __syncthreads();

    // counting-sort fill into LDS (local positions)
    for (int i = ebeg + tid; i < eend; i += 256) {
        int v = bp[i];
        int l = v & (GBKT - 1);
        int pos = atomicAdd(&cur[l], 1);
        sorted[pos] = v >> BSH;     // global src index
    }
    __syncthreads();

    // gather: 8-lane groups pull node slots dynamically
    int lane = tid & 63;
    int c = tid & 7;            // col block (8 bf16 cols = 16B)
    for (;;) {
        int slot;
        if ((tid & 7) == 0) slot = atomicAdd(&nextn, 1);
        slot = __shfl(slot, lane & 56, 64);
        if (slot >= GBKT) break;
        int node = base + slot;
        if (node >= N) continue;
        int beg = excl[slot];
        int cn = cnt[slot];
        int end = beg + cn;
        // self-loop message seeds accumulator set A
        uint4 v = ybf[(size_t)node * 8 + c];
        float4 a0 = make_float4(bflo(v.x), bfhi(v.x), bflo(v.y), bfhi(v.y));
        float4 a1 = make_float4(bflo(v.z), bfhi(v.z), bflo(v.w), bfhi(v.w));
        float4 e0 = make_float4(0.f, 0.f, 0.f, 0.f);
        float4 e1 = e0;
        int j = beg;
        for (; j + 3 < end; j += 4) {
            int s0 = sorted[j], s1 = sorted[j + 1], s2 = sorted[j + 2], s3 = sorted[j + 3];
            uint4 r0 = ybf[(size_t)s0 * 8 + c];
            uint4 r1 = ybf[(size_t)s1 * 8 + c];
            uint4 r2 = ybf[(size_t)s2 * 8 + c];
            uint4 r3 = ybf[(size_t)s3 * 8 + c];
            acc_row(r0, a0, a1);
            acc_row(r1, e0, e1);
            acc_row(r2, a0, a1);
            acc_row(r3, e0, e1);
        }
        for (; j < end; ++j) {
            uint4 r = ybf[(size_t)sorted[j] * 8 + c];
            acc_row(r, a0, a1);
        }
        a0.x += e0.x; a0.y += e0.y; a0.z += e0.z; a0.w += e0.w;
        a1.x += e1.x; a1.y += e1.y; a1.z += e1.z; a1.w += e1.w;

        float dn = rsqrtf((float)(1 + cn));
        float4 bb0 = b4[2 * c];
        float4 bb1 = b4[2 * c + 1];
        float4 o0, o1;
        o0.x = fmaxf(fmaf(a0.x, dn, bb0.x), 0.f);
        o0.y = fmaxf(fmaf(a0.y, dn, bb0.y), 0.f);
        o0.z = fmaxf(fmaf(a0.z, dn, bb0.z), 0.f);
        o0.w = fmaxf(fmaf(a0.w, dn, bb0.w), 0.f);
        o1.x = fmaxf(fmaf(a1.x, dn, bb1.x), 0.f);
        o1.y = fmaxf(fmaf(a1.y, dn, bb1.y), 0.f);
        o1.z = fmaxf(fmaf(a1.z, dn, bb1.z), 0.f);
        o1.w = fmaxf(fmaf(a1.w, dn, bb1.w), 0.f);
        out4[(size_t)node * 16 + 2 * c] = o0;
        out4[(size_t)node * 16 + 2 * c + 1] = o1;
    }
}

// ---------------- launch ----------------

extern "C" void kernel_launch(void* const* d_in, const int* in_sizes, int n_in,
                              void* d_out, int out_size, void* d_ws, size_t ws_size,
                              hipStream_t stream) {
    const float* z = (const float*)d_in[0];
    const int* ei  = (const int*)d_in[1];
    const float* W = (const float*)d_in[2];
    const float* b = (const float*)d_in[3];
    float* out = (float*)d_out;

    const int N = in_sizes[0] / DD;
    const int E = in_sizes[1] / 2;
    const int* src = ei;
    const int* dst = ei + E;

    const int NBK = (N + GBKT - 1) >> BSH;

    // workspace layout
    unsigned short* ybf = (unsigned short*)d_ws;      // 64N ushorts (bf16)
    float* dinv  = (float*)(ybf + (size_t)64 * N);    // N f
    int*   bcur  = (int*)(dinv + N);                  // NBK
    int*   bp    = bcur + NBK;                        // (NBK+1)*CAP (slack for spill)

    init_k<<<(NBK + 255) / 256, 256, 0, stream>>>(bcur, NBK);
    part_k<<<(E + TILE - 1) / TILE, PTHREADS, 0, stream>>>(src, dst, bcur, bp, E, NBK);
    nodedeg_k<<<NBK, 256, 0, stream>>>(bp, bcur, dinv, N);
    gemm_k<<<(N + 31) / 32, 512, 0, stream>>>(z, W, dinv, (ushort4*)ybf, N);
    bg_k<<<NBK, 256, 0, stream>>>((const uint4*)ybf, bp, bcur,
                                  (const float4*)b, (float4*)out, N);
}